// Round 1
// baseline (60.547 us; speedup 1.0000x reference)
//
#include <hip/hip_runtime.h>

// Overlap-add: y[b, f*256 + c] += x[b, c, f]
// x: [16, 1024, 2048] f32, y: [16, 525056] f32
// WIN/HOP = 4 -> y[b, g*256 + r] = sum_{k=0}^{3} x[b, k*256 + r, g - k]  (valid g-k)

constexpr int BATCH   = 16;
constexpr int WIN     = 1024;
constexpr int HOP     = 256;
constexpr int NF      = 2048;                      // frames
constexpr int OUT_LEN = (NF - 1) * HOP + WIN;      // 525056
constexpr int GTOT    = OUT_LEN / HOP;             // 2051
constexpr int FT      = 32;                        // g-values per block tile
constexpr int NTILES  = (GTOT + FT - 1) / FT;      // 65

// alignment-4 float4: the per-k shift (-k floats) misaligns 16B vectors;
// let the compiler emit dwordx4 (gfx9 global loads only need dword align)
typedef float f4u __attribute__((ext_vector_type(4), aligned(4)));

__global__ __launch_bounds__(256)
void oadd_kernel(const float* __restrict__ x, float* __restrict__ y) {
    // +1 pad -> phase-2 read acc[tid][j] has bank (tid + j) % 32: conflict-free
    __shared__ float acc[256][FT + 1];

    const int tid  = threadIdx.x;
    const int tile = blockIdx.x;
    const int b    = blockIdx.y;
    const int g0   = tile * FT;

    const int q  = tid & 7;    // which float4 slot: j = 4q .. 4q+3
    const int rr = tid >> 3;   // 0..31

    const float* __restrict__ xb = x + (size_t)b * WIN * NF;

    // interior iff every f = g0 + j - k (j in [0,FT), k in [0,4)) is in [0, NF)
    const bool interior = (g0 >= 3) && (g0 + FT - 1 <= NF - 1);

    if (interior) {
        #pragma unroll
        for (int ri = 0; ri < 8; ++ri) {
            const int r = ri * 32 + rr;
            float a0 = 0.f, a1 = 0.f, a2 = 0.f, a3 = 0.f;
            #pragma unroll
            for (int k = 0; k < 4; ++k) {
                const float* p = xb + (size_t)(k * HOP + r) * NF + (g0 + q * 4 - k);
                f4u v = *reinterpret_cast<const f4u*>(p);
                a0 += v.x; a1 += v.y; a2 += v.z; a3 += v.w;
            }
            float* d = &acc[r][q * 4];
            d[0] = a0; d[1] = a1; d[2] = a2; d[3] = a3;
        }
    } else {
        // boundary tiles (first and last): per-element guarded scalar loads
        for (int ri = 0; ri < 8; ++ri) {
            const int r = ri * 32 + rr;
            float a[4] = {0.f, 0.f, 0.f, 0.f};
            for (int k = 0; k < 4; ++k) {
                const size_t crow = (size_t)(k * HOP + r) * NF;
                #pragma unroll
                for (int m = 0; m < 4; ++m) {
                    const int f = g0 + q * 4 + m - k;
                    if (f >= 0 && f < NF) a[m] += xb[crow + f];
                }
            }
            float* d = &acc[r][q * 4];
            d[0] = a[0]; d[1] = a[1]; d[2] = a[2]; d[3] = a[3];
        }
    }

    __syncthreads();

    // coalesced write-out: lane tid owns r = tid for all j
    float* __restrict__ yb = y + (size_t)b * OUT_LEN;
    #pragma unroll
    for (int j = 0; j < FT; ++j) {
        const int g = g0 + j;
        if (g < GTOT) {
            yb[(size_t)g * HOP + tid] = acc[tid][j];
        }
    }
}

extern "C" void kernel_launch(void* const* d_in, const int* in_sizes, int n_in,
                              void* d_out, int out_size, void* d_ws, size_t ws_size,
                              hipStream_t stream) {
    const float* x = (const float*)d_in[0];
    float* y = (float*)d_out;
    dim3 grid(NTILES, BATCH, 1);
    oadd_kernel<<<grid, 256, 0, stream>>>(x, y);
}